// Round 1
// baseline (154.944 us; speedup 1.0000x reference)
//
#include <hip/hip_runtime.h>

// TargetAttention: scores = kv · q, softmax over heads (monotonic -> skip),
// argmax over 8 heads, gather winning 128-float row.
// B = 131072, H = 8, E = 128. Pure memory-bound gather: ~640 MB traffic.

constexpr int H = 8;
constexpr int E = 128;

__global__ __launch_bounds__(256) void TargetAttention_30142080483365_kernel(
    const float* __restrict__ q,   // [B, 1, E]
    const float* __restrict__ kv,  // [B, H, E]
    float* __restrict__ out,       // [B, E]
    int B, int total_waves) {
  const int tid  = blockIdx.x * blockDim.x + threadIdx.x;
  const int wave = tid >> 6;
  const int lane = threadIdx.x & 63;
  const int half = lane >> 5;   // 0: heads {0,2,4,6}, 1: heads {1,3,5,7}
  const int l32  = lane & 31;

  for (int b = wave; b < B; b += total_waves) {
    // Per-lane query fragment: q[b, 4*l32 .. 4*l32+3] (same for both halves).
    const float4* qv = reinterpret_cast<const float4*>(q + (size_t)b * E);
    const float4 qf = qv[l32];

    // kv tile for this b: 1024 floats = 256 float4. Four coalesced wave loads.
    // float4 index i*64+lane -> head 2i+half, row elements 4*l32 .. 4*l32+3.
    const float4* kvt = reinterpret_cast<const float4*>(kv + (size_t)b * (H * E));
    float s[4];
#pragma unroll
    for (int i = 0; i < 4; ++i) {
      const float4 kf = kvt[i * 64 + lane];
      s[i] = kf.x * qf.x + kf.y * qf.y + kf.z * qf.z + kf.w * qf.w;
    }

    // Tree-reduce each partial dot across the 32-lane half-wave.
#pragma unroll
    for (int m = 1; m < 32; m <<= 1) {
#pragma unroll
      for (int i = 0; i < 4; ++i) s[i] += __shfl_xor(s[i], m, 64);
    }

    // Exchange the 4 scores with the other half -> every lane has all 8.
    float o[4];
#pragma unroll
    for (int i = 0; i < 4; ++i) o[i] = __shfl_xor(s[i], 32, 64);

    float sc[8];
#pragma unroll
    for (int i = 0; i < 4; ++i) {
      sc[2 * i + half] = s[i];
      sc[2 * i + (half ^ 1)] = o[i];
    }

    // First-occurrence argmax (strict >) matches np.argmax tie-breaking.
    int idx = 0;
    float best = sc[0];
#pragma unroll
    for (int h = 1; h < H; ++h) {
      if (sc[h] > best) { best = sc[h]; idx = h; }
    }

    // Gather the winning row: 128 floats = 64 lanes x float2 (cache-hot).
    const float2* src =
        reinterpret_cast<const float2*>(kv + (size_t)b * (H * E) + (size_t)idx * E);
    float2* dst = reinterpret_cast<float2*>(out + (size_t)b * E);
    dst[lane] = src[lane];
  }
}

extern "C" void kernel_launch(void* const* d_in, const int* in_sizes, int n_in,
                              void* d_out, int out_size, void* d_ws, size_t ws_size,
                              hipStream_t stream) {
  const float* q  = (const float*)d_in[0];   // [B,1,E]
  const float* kv = (const float*)d_in[1];   // [B,H,E]
  float* out = (float*)d_out;                // [B,E]
  const int B = in_sizes[0] / E;             // 131072

  const int blocks = 2048;                   // 4 waves/block -> 8192 waves
  const int threads = 256;
  const int total_waves = blocks * (threads / 64);
  TargetAttention_30142080483365_kernel<<<blocks, threads, 0, stream>>>(
      q, kv, out, B, total_waves);
}

// Round 3
// 121.985 us; speedup vs baseline: 1.2702x; 1.2702x over previous
//
#include <hip/hip_runtime.h>

// TargetAttention: scores = kv · q, softmax over heads (monotonic -> skip),
// argmax over 8 heads (first-occurrence), output winning 128-float row.
// B = 131072, H = 8, E = 128. Memory-bound: 576 MB read + 64 MB write.
//
// v2b: winning row written FROM REGISTERS (no dependent gather re-read),
// reduce-scatter + packed argmax butterfly (~12 shuffles vs 24),
// non-temporal loads/stores via clang ext_vector_type (HIP float4 is a
// class type the builtin rejects).

constexpr int H = 8;
constexpr int E = 128;

typedef float f32x4 __attribute__((ext_vector_type(4)));

__global__ __launch_bounds__(256) void TargetAttention_30142080483365_kernel(
    const float* __restrict__ q,   // [B, 1, E]
    const float* __restrict__ kv,  // [B, H, E]
    float* __restrict__ out,       // [B, E]
    int B, int total_waves) {
  const int tid  = blockIdx.x * blockDim.x + threadIdx.x;
  const int wave = tid >> 6;
  const int lane = threadIdx.x & 63;
  const int half = lane >> 5;   // head parity this lane's fragments belong to
  const int l32  = lane & 31;

  for (int b = wave; b < B; b += total_waves) {
    // Per-lane query fragment: q[b, 4*l32 .. 4*l32+3] (same in both halves).
    const f32x4* qv = reinterpret_cast<const f32x4*>(q + (size_t)b * E);
    const f32x4 qf = __builtin_nontemporal_load(&qv[l32]);

    // kv tile: 1024 floats = 256 float4 -> 4 perfectly coalesced wave loads.
    // float4 index i*64+lane -> head 2i+half, row elements 4*l32 .. 4*l32+3.
    const f32x4* kvt = reinterpret_cast<const f32x4*>(kv + (size_t)b * (H * E));
    const f32x4 kf0 = __builtin_nontemporal_load(&kvt[0 * 64 + lane]);
    const f32x4 kf1 = __builtin_nontemporal_load(&kvt[1 * 64 + lane]);
    const f32x4 kf2 = __builtin_nontemporal_load(&kvt[2 * 64 + lane]);
    const f32x4 kf3 = __builtin_nontemporal_load(&kvt[3 * 64 + lane]);

    float s0 = kf0.x * qf.x + kf0.y * qf.y + kf0.z * qf.z + kf0.w * qf.w;
    float s1 = kf1.x * qf.x + kf1.y * qf.y + kf1.z * qf.z + kf1.w * qf.w;
    float s2 = kf2.x * qf.x + kf2.y * qf.y + kf2.z * qf.z + kf2.w * qf.w;
    float s3 = kf3.x * qf.x + kf3.y * qf.y + kf3.z * qf.z + kf3.w * qf.w;

    // --- Reduce-scatter: 4 partials/lane -> 1 partial/lane --------------
    // mask 16: lanes bit16=0 accumulate {s0,s1} (i=0,1), bit16=1 -> {s2,s3}.
    const bool hi16 = (lane & 16) != 0;
    {
      float x = hi16 ? s0 : s2;
      float y = hi16 ? s1 : s3;
      float xr = __shfl_xor(x, 16, 64);
      float yr = __shfl_xor(y, 16, 64);
      s0 = (hi16 ? s2 : s0) + xr;   // a0: i = hi16 ? 2 : 0
      s1 = (hi16 ? s3 : s1) + yr;   // a1: i = hi16 ? 3 : 1
    }
    // mask 8: bit8=0 keeps a0, bit8=1 keeps a1.
    const bool hi8 = (lane & 8) != 0;
    float v;
    {
      float z = hi8 ? s0 : s1;
      float zr = __shfl_xor(z, 8, 64);
      v = (hi8 ? s1 : s0) + zr;
    }
    // Finish the sum over the remaining 8-lane group (masks 4,2,1).
    v += __shfl_xor(v, 4, 64);
    v += __shfl_xor(v, 2, 64);
    v += __shfl_xor(v, 1, 64);

    // This lane now holds the full score of:
    //   head = 4*bit16 + 2*bit8 + half   (head <-> lane bits {5,4,3})
    int bh = 4 * (int)hi16 + 2 * (int)hi8 + half;
    float bs = v;

    // --- Argmax butterfly over lane bits 3,4,5 (covers all 8 heads) ----
    // First-occurrence semantics: strict >, ties keep smaller head index.
#pragma unroll
    for (int m = 8; m <= 32; m <<= 1) {
      float os = __shfl_xor(bs, m, 64);
      int oh = __shfl_xor(bh, m, 64);
      if (os > bs || (os == bs && oh < bh)) { bs = os; bh = oh; }
    }
    // (bs, bh) now wave-uniform.

    // --- Write winning row from registers ------------------------------
    // Row bh lives in fragment (bh>>1) of the lanes with half == (bh&1).
    const int fi = bh >> 1;
    f32x4 w01 = (fi & 1) ? kf1 : kf0;
    f32x4 w23 = (fi & 1) ? kf3 : kf2;
    f32x4 w = (fi & 2) ? w23 : w01;
    if (half == (bh & 1)) {
      f32x4* dst = reinterpret_cast<f32x4*>(out + (size_t)b * E);
      __builtin_nontemporal_store(w, &dst[l32]);  // 32 lanes x 16B = 512B
    }
  }
}

extern "C" void kernel_launch(void* const* d_in, const int* in_sizes, int n_in,
                              void* d_out, int out_size, void* d_ws, size_t ws_size,
                              hipStream_t stream) {
  const float* q  = (const float*)d_in[0];   // [B,1,E]
  const float* kv = (const float*)d_in[1];   // [B,H,E]
  float* out = (float*)d_out;                // [B,E]
  const int B = in_sizes[0] / E;             // 131072

  const int blocks = 2048;                   // 4 waves/block -> 8192 waves
  const int threads = 256;
  const int total_waves = blocks * (threads / 64);
  TargetAttention_30142080483365_kernel<<<blocks, threads, 0, stream>>>(
      q, kv, out, B, total_waves);
}